// Round 1
// baseline (762.598 us; speedup 1.0000x reference)
//
#include <hip/hip_runtime.h>

// RNN-T (Transducer) forward loss on MI355X.
// Two dispatches:
//   1) gather_kernel: scatter-gather blank/label log-scores from the 662 MB
//      logits tensor into a compact DIAGONAL-major float4 layout in d_ws,
//      so the scan kernel reads one coalesced float4 per lane per step.
//      Also zeroes d_out (harness poisons it with 0xAA before every launch).
//   2) scan_kernel: 1 wave per batch element; 300 serial anti-diagonal steps
//      of alpha[t][u] = logaddexp(alpha[t-1][u]+blank, alpha[t][u-1]+lab).
//      Lane L owns columns u=L and u=L+64. PF-deep register prefetch hides
//      L2/L3 latency of the compact-array reads.

#define NEGC (-1e30f)

constexpr int B  = 8;
constexpr int T  = 200;
constexpr int U  = 100;
constexpr int U1 = 101;
constexpr int V  = 1024;
constexpr int DIAG = T + U1 - 1;   // 300 anti-diagonals
constexpr int PF   = 12;           // prefetch depth (300 % 12 == 0)
constexpr int DPAD = DIAG + PF;    // 312 rows allocated (prefetch overrun pad)
// ws layout: float4 diag4[B][DPAD][64]
//   diag4[b][d][L] = { blank(t=d-L-1, u=L), lab(t=d-L, u=L, via labels[L-1]),
//                      blank(t=d-L-65, u=L+64), lab(t=d-L-64, u=L+64) }
// ws bytes needed: 8*312*64*16 = 2,555,904

__device__ __forceinline__ float lae(float x, float y) {
    // logaddexp; threshold is lenient (abs ~4.6) so fast exp/log are fine.
    float m = fmaxf(x, y);
    float e = __expf(-fabsf(x - y));
    return m + __logf(1.0f + e);
}

__global__ __launch_bounds__(128) void TransducerLoss_67894843015619_gather(
    const float* __restrict__ logits, const int* __restrict__ labels,
    float* __restrict__ diag4, float* __restrict__ out)
{
    int u  = threadIdx.x;
    int bd = blockIdx.x;
    int b  = bd / DIAG;
    int d  = bd - b * DIAG;
    if (bd == 0 && u == 0) out[0] = 0.0f;
    if (u >= U1) return;

    int t = d - u;
    float bk = NEGC, lc = NEGC;
    if (t >= 0 && t < T) {
        const float* lb = logits + (size_t)b * T * U1 * V;
        if (t >= 1) bk = lb[(size_t)((t - 1) * U1 + u) * V];          // blank[b][t-1][u]
        if (u >= 1) {
            int lab = labels[b * U + (u - 1)];
            lc = lb[(size_t)(t * U1 + (u - 1)) * V + lab];            // lab[b][t][u-1]
        }
    }
    int lane = u & 63, slot = u >> 6;
    float* p = diag4 + (((size_t)b * DPAD + d) * 64 + lane) * 4 + slot * 2;
    p[0] = bk;
    p[1] = lc;
}

__global__ __launch_bounds__(64) void TransducerLoss_67894843015619_scan(
    const float* __restrict__ diag4f,
    const int* __restrict__ logit_lengths, const int* __restrict__ label_lengths,
    float* __restrict__ out)
{
    int b = blockIdx.x;
    int L = threadIdx.x;          // lane 0..63
    int u0 = L, u1 = L + 64;      // the two grid columns this lane owns
    int Tb  = logit_lengths[b];
    int Ubl = label_lengths[b];

    const float4* base = (const float4*)diag4f + (size_t)b * DPAD * 64 + L;
    // step d's data: base[d * 64]

    float4 pf[PF];
#pragma unroll
    for (int k = 0; k < PF; ++k) pf[k] = base[(size_t)k * 64];

    float a0 = NEGC, a1 = NEGC;   // alpha for (t=d-u0, u0) and (t=d-u1, u1)
    float contrib = 0.0f;

    for (int db = 0; db < DIAG; db += PF) {
#pragma unroll
        for (int k = 0; k < PF; ++k) {
            int d = db + k;
            float4 v = pf[k];
            pf[k] = base[(size_t)(d + PF) * 64];   // prefetch step d+PF

            int t0 = d - u0, t1 = d - u1;

            // left neighbors use PREVIOUS-step alphas (read before commit)
            float left0 = __shfl_up(a0, 1);
            float left1 = __shfl_up(a1, 1);
            float a63   = __shfl(a0, 63);
            if (L == 0) left1 = a63;               // u=64's left is u=63 (slot0 lane63)

            float term0 = (u0 == 0) ? NEGC : left0 + v.y;
            float base0 = (t0 == 0) ? ((u0 == 0) ? 0.0f : NEGC) : a0 + v.x;
            float n0 = lae(base0, term0);

            float term1 = left1 + v.w;             // u1 >= 64, always has a left
            float base1 = (t1 == 0) ? NEGC : a1 + v.z;
            float n1 = lae(base1, term1);

            if (t0 >= 0 && t0 < T) a0 = n0;
            if (t1 >= 0 && t1 < T) a1 = n1;

            if (t0 == Tb - 1 && u0 == Ubl) contrib = -n0 * 0.125f;  // /B
            if (t1 == Tb - 1 && u1 == Ubl) contrib = -n1 * 0.125f;
        }
    }

    // exactly one lane-slot per wave captured; sum across the wave
#pragma unroll
    for (int off = 32; off > 0; off >>= 1)
        contrib += __shfl_down(contrib, off);
    if (L == 0) atomicAdd(out, contrib);
}

extern "C" void kernel_launch(void* const* d_in, const int* in_sizes, int n_in,
                              void* d_out, int out_size, void* d_ws, size_t ws_size,
                              hipStream_t stream) {
    const float* logits        = (const float*)d_in[0];
    const int*   labels        = (const int*)d_in[1];
    const int*   logit_lengths = (const int*)d_in[2];
    const int*   label_lengths = (const int*)d_in[3];
    float* out   = (float*)d_out;
    float* diag4 = (float*)d_ws;   // needs 2,555,904 bytes

    TransducerLoss_67894843015619_gather<<<B * DIAG, 128, 0, stream>>>(
        logits, labels, diag4, out);
    TransducerLoss_67894843015619_scan<<<B, 64, 0, stream>>>(
        diag4, logit_lengths, label_lengths, out);
}

// Round 2
// 757.894 us; speedup vs baseline: 1.0062x; 1.0062x over previous
//
#include <hip/hip_runtime.h>

// RNN-T (Transducer) forward loss on MI355X.
// Two dispatches:
//   1) gather: scatter-gather blank/label log-scores from the 662 MB logits
//      tensor into a compact DIAGONAL-major float4 layout in d_ws (2.5 MB),
//      so the scan kernel reads one coalesced float4 per lane per step.
//      Also zeroes d_out (harness poisons it with 0xAA before every launch).
//   2) scan: 1 wave per batch element; 300 serial anti-diagonal steps of
//      alpha[t][u] = logaddexp(alpha[t-1][u]+blank, alpha[t][u-1]+lab).
//      Lane L owns columns u=L and u=L+64. PF=12 register prefetch keeps the
//      compact-array reads ~2400 cycles ahead of use (covers L2/HBM latency).
//
// R1 profile evidence: timed window is dominated by harness resets
// (fillBufferAligned 2.47 GiB @ ~418 us ~80% HBM peak, + 662 MB d_in restore
// ~200 us). Our kernels are est. <30 us combined. This round: micro-opts only
// (float2 store in gather) to confirm the harness-reset floor hypothesis.

#define NEGC (-1e30f)

constexpr int B  = 8;
constexpr int T  = 200;
constexpr int U  = 100;
constexpr int U1 = 101;
constexpr int V  = 1024;
constexpr int DIAG = T + U1 - 1;   // 300 anti-diagonals
constexpr int PF   = 12;           // prefetch depth (300 % 12 == 0)
constexpr int DPAD = DIAG + PF;    // prefetch overrun pad
// ws layout: float4 diag4[B][DPAD][64]
//   diag4[b][d][L] = { blank(t=d-L-1, u=L), lab(t=d-L, u=L),
//                      blank(t=d-L-65, u=L+64), lab(t=d-L-64, u=L+64) }
// ws bytes needed: 8*312*64*16 = 2,555,904

__device__ __forceinline__ float lae(float x, float y) {
    float m = fmaxf(x, y);
    float e = __expf(-fabsf(x - y));
    return m + __logf(1.0f + e);
}

__global__ __launch_bounds__(128) void TransducerLoss_67894843015619_gather(
    const float* __restrict__ logits, const int* __restrict__ labels,
    float* __restrict__ diag4, float* __restrict__ out)
{
    int u  = threadIdx.x;
    int bd = blockIdx.x;
    int b  = bd / DIAG;
    int d  = bd - b * DIAG;
    if (bd == 0 && u == 0) out[0] = 0.0f;
    if (u >= U1) return;

    int t = d - u;
    float bk = NEGC, lc = NEGC;
    if (t >= 0 && t < T) {
        const float* lb = logits + (size_t)b * T * U1 * V;
        if (t >= 1) bk = lb[(size_t)((t - 1) * U1 + u) * V];          // blank[b][t-1][u]
        if (u >= 1) {
            int lab = labels[b * U + (u - 1)];
            lc = lb[(size_t)(t * U1 + (u - 1)) * V + lab];            // lab[b][t][u-1]
        }
    }
    int lane = u & 63, slot = u >> 6;
    float2* p = (float2*)(diag4 + (((size_t)b * DPAD + d) * 64 + lane) * 4) + slot;
    *p = make_float2(bk, lc);
}

__global__ __launch_bounds__(64) void TransducerLoss_67894843015619_scan(
    const float* __restrict__ diag4f,
    const int* __restrict__ logit_lengths, const int* __restrict__ label_lengths,
    float* __restrict__ out)
{
    int b = blockIdx.x;
    int L = threadIdx.x;          // lane 0..63
    int u0 = L, u1 = L + 64;      // the two grid columns this lane owns
    int Tb  = logit_lengths[b];
    int Ubl = label_lengths[b];

    const float4* base = (const float4*)diag4f + (size_t)b * DPAD * 64 + L;

    float4 pf[PF];
#pragma unroll
    for (int k = 0; k < PF; ++k) pf[k] = base[(size_t)k * 64];

    float a0 = NEGC, a1 = NEGC;
    float contrib = 0.0f;

    for (int db = 0; db < DIAG; db += PF) {
#pragma unroll
        for (int k = 0; k < PF; ++k) {
            int d = db + k;
            float4 v = pf[k];
            pf[k] = base[(size_t)(d + PF) * 64];   // prefetch step d+PF

            int t0 = d - u0, t1 = d - u1;

            float left0 = __shfl_up(a0, 1);
            float left1 = __shfl_up(a1, 1);
            float a63   = __shfl(a0, 63);
            if (L == 0) left1 = a63;               // u=64's left is u=63

            float term0 = (u0 == 0) ? NEGC : left0 + v.y;
            float base0 = (t0 == 0) ? ((u0 == 0) ? 0.0f : NEGC) : a0 + v.x;
            float n0 = lae(base0, term0);

            float term1 = left1 + v.w;
            float base1 = (t1 == 0) ? NEGC : a1 + v.z;
            float n1 = lae(base1, term1);

            if (t0 >= 0 && t0 < T) a0 = n0;
            if (t1 >= 0 && t1 < T) a1 = n1;

            if (t0 == Tb - 1 && u0 == Ubl) contrib = -n0 * 0.125f;  // /B (mean)
            if (t1 == Tb - 1 && u1 == Ubl) contrib = -n1 * 0.125f;
        }
    }

#pragma unroll
    for (int off = 32; off > 0; off >>= 1)
        contrib += __shfl_down(contrib, off);
    if (L == 0) atomicAdd(out, contrib);
}

extern "C" void kernel_launch(void* const* d_in, const int* in_sizes, int n_in,
                              void* d_out, int out_size, void* d_ws, size_t ws_size,
                              hipStream_t stream) {
    const float* logits        = (const float*)d_in[0];
    const int*   labels        = (const int*)d_in[1];
    const int*   logit_lengths = (const int*)d_in[2];
    const int*   label_lengths = (const int*)d_in[3];
    float* out   = (float*)d_out;
    float* diag4 = (float*)d_ws;   // needs 2,555,904 bytes

    TransducerLoss_67894843015619_gather<<<B * DIAG, 128, 0, stream>>>(
        logits, labels, diag4, out);
    TransducerLoss_67894843015619_scan<<<B, 64, 0, stream>>>(
        diag4, logit_lengths, label_lengths, out);
}